// Round 1
// baseline (1144.388 us; speedup 1.0000x reference)
//
#include <hip/hip_runtime.h>

// irreps lifting tensor product: per l in {0,1,2}, d=2l+1:
//   out[n, OFF_OUT + w*d + i] = (1/8) * sum_u x[n, OFF_IN + u*d + i] * W_l[u][w]
// N=100000, MUL_IN=64 (K), MUL_OUT=256, x row = 576 fp32, out row = 2304 fp32.

typedef __attribute__((ext_vector_type(8))) short bf16x8;   // 8 bf16 = 4 VGPRs
typedef __attribute__((ext_vector_type(4))) float f32x4;    // MFMA accumulator

__device__ __forceinline__ unsigned short f2bf(float f) {
  // fp32 -> bf16 round-to-nearest-even (inputs are finite normals)
  union { float f; unsigned u; } a; a.f = f;
  unsigned r = a.u + 0x7fffu + ((a.u >> 16) & 1u);
  return (unsigned short)(r >> 16);
}

template<int D, int TM, int OFF_IN, int OFF_OUT>
__launch_bounds__(256)
__global__ void tp_kernel(const float* __restrict__ x, const float* __restrict__ W,
                          float* __restrict__ out, int n_total) {
  constexpr int SP       = 72;        // LDS A row stride in bf16 (pad 64 -> 72; 144B rows, 16B aligned)
  constexpr int MROWS    = TM * D;    // A rows: m = local_n*D + i
  constexpr int RT       = MROWS / 16;
  constexpr int ROWELEMS = 64 * D;    // fp32 elems of x per n-row for this l
  constexpr int HALF     = 128 * D;   // out floats per n-row per epilogue phase (w split in halves)
  constexpr int SMEM_A   = MROWS * SP * 2;
  constexpr int SMEM_C   = TM * HALF * 4;
  constexpr int SMEM     = (SMEM_C > SMEM_A) ? SMEM_C : SMEM_A;

  __shared__ __align__(16) char smraw[SMEM];
  unsigned short* sa = (unsigned short*)smraw;  // A stage: sa[m][u], stride SP
  float*          sc = (float*)smraw;           // C stage (reused after MFMA)

  const int tid  = threadIdx.x;
  const int wv   = tid >> 6;        // wave 0..3 -> w in [wv*64, wv*64+64)
  const int lane = tid & 63;
  const int quad = lane >> 4;
  const int nc   = lane & 15;
  const int n0   = blockIdx.x * TM;

  // ---- B fragments: weights, loaded once (L2-resident, shared by all blocks) ----
  // B[k=u][col=w]: col = lane&15, k = quad*8 + j (+ 32*s)
  bf16x8 bfrag[4][2];
#pragma unroll
  for (int t = 0; t < 4; ++t) {
#pragma unroll
    for (int s = 0; s < 2; ++s) {
      const int w = wv * 64 + t * 16 + nc;
#pragma unroll
      for (int j = 0; j < 8; ++j) {
        const int u = s * 32 + quad * 8 + j;
        bfrag[t][s][j] = (short)f2bf(W[u * 256 + w]);
      }
    }
  }

  // ---- stage A: coalesced float4 global reads -> bf16 LDS, (u,i) transposed ----
  constexpr int STAGE_IT = (TM * ROWELEMS / 4) / 256;
#pragma unroll
  for (int it = 0; it < STAGE_IT; ++it) {
    const int F  = (tid + it * 256) * 4;
    const int ln = F / ROWELEMS;
    const int e  = F % ROWELEMS;     // e = u*D + i, 4 consecutive
    const int n  = n0 + ln;
    float4 v = make_float4(0.f, 0.f, 0.f, 0.f);
    if (n < n_total) v = *(const float4*)(x + (size_t)n * 576 + OFF_IN + e);
    const float vv[4] = {v.x, v.y, v.z, v.w};
#pragma unroll
    for (int k = 0; k < 4; ++k) {
      const int ek = e + k;
      const int u  = ek / D;
      const int i  = ek % D;
      sa[(ln * D + i) * SP + u] = f2bf(vv[k]);
    }
  }
  __syncthreads();

  // ---- MFMA: acc[r][t] = A(rows r*16..) * B(cols wv*64+t*16..) over K=64 ----
  f32x4 acc[RT][4];
#pragma unroll
  for (int r = 0; r < RT; ++r)
#pragma unroll
    for (int t = 0; t < 4; ++t)
      acc[r][t] = (f32x4){0.f, 0.f, 0.f, 0.f};

#pragma unroll
  for (int r = 0; r < RT; ++r) {
#pragma unroll
    for (int s = 0; s < 2; ++s) {
      // A[m=lane&15][k=quad*8+j]; row stride SP bf16 -> 144B, 16B-aligned ds_read_b128
      const bf16x8 af = *(const bf16x8*)(sa + (r * 16 + nc) * SP + s * 32 + quad * 8);
#pragma unroll
      for (int t = 0; t < 4; ++t)
        acc[r][t] = __builtin_amdgcn_mfma_f32_16x16x32_bf16(af, bfrag[t][s], acc[r][t], 0, 0, 0);
    }
  }

  // ---- epilogue: 2 phases over w-halves; stage C in LDS, then contiguous float4 stores ----
  constexpr int OUT_IT = (TM * HALF / 4) / 256;
#pragma unroll
  for (int h = 0; h < 2; ++h) {
    __syncthreads();                  // phase 0: protects sa; phase 1: protects prior sc reads
    if ((wv >> 1) == h) {             // waves owning w in [h*128, h*128+128)
#pragma unroll
      for (int r = 0; r < RT; ++r) {
#pragma unroll
        for (int t = 0; t < 4; ++t) {
          const int wl = wv * 64 + t * 16 + nc - h * 128;  // 0..127
#pragma unroll
          for (int reg = 0; reg < 4; ++reg) {
            const int m  = r * 16 + quad * 4 + reg;        // C row = quad*4+reg
            const int ln = m / D;
            const int i  = m % D;
            sc[(ln * 128 + wl) * D + i] = acc[r][t][reg] * 0.125f;
          }
        }
      }
    }
    __syncthreads();
#pragma unroll
    for (int it = 0; it < OUT_IT; ++it) {
      const int F  = (tid + it * 256) * 4;
      const int ln = F / HALF;
      const int p  = F % HALF;
      const int n  = n0 + ln;
      if (n < n_total)
        *(float4*)(out + (size_t)n * 2304 + OFF_OUT + h * HALF + p) = *(const float4*)(sc + F);
    }
  }
}

extern "C" void kernel_launch(void* const* d_in, const int* in_sizes, int n_in,
                              void* d_out, int out_size, void* d_ws, size_t ws_size,
                              hipStream_t stream) {
  const float* x  = (const float*)d_in[0];
  const float* W0 = (const float*)d_in[1];
  const float* W1 = (const float*)d_in[2];
  const float* W2 = (const float*)d_in[3];
  float* out = (float*)d_out;
  const int n = in_sizes[0] / 576;

  // l=0 (d=1): TM=64 rows/block; l=1 (d=3), l=2 (d=5): TM=16 (TM*D % 16 == 0)
  tp_kernel<1, 64,   0,    0><<<(n + 63) / 64, 256, 0, stream>>>(x, W0, out, n);
  tp_kernel<3, 16,  64,  256><<<(n + 15) / 16, 256, 0, stream>>>(x, W1, out, n);
  tp_kernel<5, 16, 256, 1024><<<(n + 15) / 16, 256, 0, stream>>>(x, W2, out, n);
}